// Round 1
// baseline (223.524 us; speedup 1.0000x reference)
//
#include <hip/hip_runtime.h>

typedef unsigned int u32;
typedef unsigned short u16;
typedef unsigned long long u64;

typedef __attribute__((ext_vector_type(4))) float f32x4;
typedef __attribute__((ext_vector_type(8))) __bf16 bf16x8;
typedef __attribute__((ext_vector_type(8))) u16 u16x8;
typedef __attribute__((ext_vector_type(4))) u16 u16x4;

#define NB 256
#define ND 512
#define NC 100000
#define NC4 25000            // NC/4 float4s per row
#define CAP 1048576          // collect buffer entries

// ---- ws layout (bytes) ----
#define OFF_EMBN  0                   // u16 [256*512]            = 262144
#define OFF_COLSS 262144              // f32 [100000] (+pad)      -> 662528
#define OFF_COS   662528              // f32 [256*100000]         = 102400000
#define OFF_TGT   103062528           // f32 [256]
#define OFF_CNT   103063552           // u32 [256]
#define OFF_SSQ   103064576           // f32 [256]
#define OFF_SEXP  103065600           // f32 [256]
#define OFF_AMAX  103066624           // u32 [256]
#define OFF_SCAL  103067648           // u32 [..] {topk, gcnt, b1, r1, negth}
#define OFF_HIST  103067904           // u32 [4096] = 16384
#define OFF_BUF   103084288           // u32 [CAP]  = 4194304

__device__ __forceinline__ u32 ordkey(float f) {
  u32 u = __float_as_uint(f);
  return (u & 0x80000000u) ? ~u : (u | 0x80000000u);
}
__device__ __forceinline__ u16 f2bf(float x) {  // RNE f32->bf16
  u32 u = __float_as_uint(x);
  return (u16)((u + 0x7FFFu + ((u >> 16) & 1u)) >> 16);
}

// ---------------- K0: normalize embeddings rows -> bf16 ----------------
__global__ void k_prep(const float* __restrict__ emb, u16* __restrict__ embn) {
  __shared__ float s[128];
  const int r = blockIdx.x, t = threadIdx.x;
  float4 v = *(const float4*)(emb + r * ND + t * 4);
  s[t] = v.x * v.x + v.y * v.y + v.z * v.z + v.w * v.w;
  __syncthreads();
  for (int st = 64; st > 0; st >>= 1) { if (t < st) s[t] += s[t + st]; __syncthreads(); }
  const float rinv = 1.0f / sqrtf(s[0]);
  u16x4 o = { f2bf(v.x * rinv), f2bf(v.y * rinv), f2bf(v.z * rinv), f2bf(v.w * rinv) };
  *(u16x4*)(embn + r * ND + t * 4) = o;
}

// ---------------- K1: kernel column sum-of-squares (deterministic) -----
__global__ void k_colss(const float* __restrict__ kern, float* __restrict__ colss) {
  __shared__ float s[256];
  const int t = threadIdx.x;
  const int c = blockIdx.x * 64 + (t & 63);
  const int dq = t >> 6;
  float acc = 0.f;
  if (c < NC) {
    const float* p = kern + (size_t)dq * 128 * NC + c;
    #pragma unroll 4
    for (int d = 0; d < 128; ++d) { float x = p[(size_t)d * NC]; acc += x * x; }
  }
  s[t] = acc;
  __syncthreads();
  if (t < 64) {
    float tot = s[t] + s[t + 64] + s[t + 128] + s[t + 192];
    if (c < NC) colss[c] = tot;
  }
}

// ---------------- K2: bf16 MFMA GEMM, cos = clip(embn @ kern / colnorm) -
// tile: M=256 (all rows) x N=128, K-steps of 64. 8 waves = 2(M) x 4(N).
__global__ __launch_bounds__(512) void k_gemm(const float* __restrict__ kern,
                                              const u16* __restrict__ embn,
                                              const float* __restrict__ colss,
                                              float* __restrict__ cosb) {
  __shared__ u16 At[256 * 72];   // [m][k] pad 72 (rows 144B, 16B aligned)
  __shared__ u16 Bt[64 * 132];   // [k][n] pad 132 (rows 264B)
  const int tid = threadIdx.x;
  const int lane = tid & 63;
  const int w = tid >> 6;
  const int mbase = (w >> 2) * 128, nbase = (w & 3) * 32;
  const int l15 = lane & 15, g = lane >> 4;
  const int cblk = blockIdx.x * 128;

  f32x4 acc[8][2];
  #pragma unroll
  for (int i = 0; i < 8; ++i)
    for (int j = 0; j < 2; ++j) acc[i][j] = (f32x4){0.f, 0.f, 0.f, 0.f};

  const int am = tid >> 1, ah = (tid & 1) * 32;   // A staging
  const int bc4 = (tid & 31) * 4, bd = tid >> 5;  // B staging

  for (int ks = 0; ks < 8; ++ks) {
    const int k0 = ks * 64;
    // stage A [256][64] from embn (bf16, global/L2)
    #pragma unroll
    for (int j = 0; j < 4; ++j) {
      u16x8 v = *(const u16x8*)(embn + am * ND + k0 + ah + j * 8);
      *(u16x8*)(At + am * 72 + ah + j * 8) = v;
    }
    // stage B [64][128] from kern fp32 -> bf16
    #pragma unroll
    for (int i = 0; i < 4; ++i) {
      const int d = bd + i * 16;
      const int gc = cblk + bc4;
      const float* src = kern + (size_t)(k0 + d) * NC + gc;
      float x0 = 0.f, x1 = 0.f, x2 = 0.f, x3 = 0.f;
      if (gc + 3 < NC) {
        float4 f = *(const float4*)src;
        x0 = f.x; x1 = f.y; x2 = f.z; x3 = f.w;
      } else {
        if (gc + 0 < NC) x0 = src[0];
        if (gc + 1 < NC) x1 = src[1];
        if (gc + 2 < NC) x2 = src[2];
        if (gc + 3 < NC) x3 = src[3];
      }
      u16x4 b4 = { f2bf(x0), f2bf(x1), f2bf(x2), f2bf(x3) };
      *(u16x4*)(Bt + d * 132 + bc4) = b4;
    }
    __syncthreads();
    #pragma unroll
    for (int kf = 0; kf < 2; ++kf) {
      bf16x8 bfr[2];
      #pragma unroll
      for (int nf = 0; nf < 2; ++nf) {
        const int n = nbase + nf * 16 + l15;
        u16x8 bu;
        #pragma unroll
        for (int i = 0; i < 8; ++i) bu[i] = Bt[(kf * 32 + g * 8 + i) * 132 + n];
        bfr[nf] = __builtin_bit_cast(bf16x8, bu);
      }
      #pragma unroll
      for (int mf = 0; mf < 8; ++mf) {
        const int m = mbase + mf * 16 + l15;
        bf16x8 av = *(const bf16x8*)(At + m * 72 + kf * 32 + g * 8);
        acc[mf][0] = __builtin_amdgcn_mfma_f32_16x16x32_bf16(av, bfr[0], acc[mf][0], 0, 0, 0);
        acc[mf][1] = __builtin_amdgcn_mfma_f32_16x16x32_bf16(av, bfr[1], acc[mf][1], 0, 0, 0);
      }
    }
    __syncthreads();
  }
  // epilogue: scale by 1/colnorm, clip, store. C/D: col=lane&15, row=(lane>>4)*4+reg
  #pragma unroll
  for (int nf = 0; nf < 2; ++nf) {
    const int c = cblk + nbase + nf * 16 + l15;
    if (c >= NC) continue;
    const float cinv = 1.0f / sqrtf(colss[c]);
    #pragma unroll
    for (int mf = 0; mf < 8; ++mf) {
      const int mrow = mbase + mf * 16 + g * 4;
      #pragma unroll
      for (int r = 0; r < 4; ++r) {
        float v = acc[mf][nf][r] * cinv;
        v = fminf(fmaxf(v, -1.0f), 1.0f);
        cosb[(size_t)(mrow + r) * NC + c] = v;
      }
    }
  }
}

// ---------------- K3: per-row scan: topk count, 12-bit hist, argmax ----
__global__ __launch_bounds__(1024) void k_scan1(const float* __restrict__ cosb,
                                                const int* __restrict__ lab,
                                                float* __restrict__ tgtws,
                                                u32* __restrict__ amaxws,
                                                u32* __restrict__ topkg,
                                                u32* __restrict__ ghist) {
  __shared__ u32 hist[4096];
  __shared__ u64 samax[1024];
  __shared__ u32 scnt[1024];
  __shared__ float stgt;
  const int tid = threadIdx.x, r = blockIdx.x;
  for (int i = tid; i < 4096; i += 1024) hist[i] = 0;
  const int lb = lab[r];
  if (tid == 0) { float tg0 = cosb[(size_t)r * NC + lb]; stgt = tg0; tgtws[r] = tg0; }
  __syncthreads();
  const float tg = stgt;
  const float* row = cosb + (size_t)r * NC;
  u32 cnt = 0; u64 best = 0;
  for (int i = tid; i < NC4; i += 1024) {
    float4 v4 = *(const float4*)(row + i * 4);
    float vv[4] = { v4.x, v4.y, v4.z, v4.w };
    #pragma unroll
    for (int j = 0; j < 4; ++j) {
      const int c = i * 4 + j;
      const float v = vv[j];
      const float tmp = (c == lb) ? (tg - 2.0f) : v;
      if (tmp > tg) cnt++;
      else atomicAdd(&hist[ordkey(tmp) >> 20], 1u);
      u64 pk = ((u64)ordkey(v) << 32) | (u32)(0xFFFFFFFFu - (u32)c);
      if (pk > best) best = pk;
    }
  }
  scnt[tid] = cnt; samax[tid] = best;
  __syncthreads();
  for (int st = 512; st > 0; st >>= 1) {
    if (tid < st) {
      scnt[tid] += scnt[tid + st];
      if (samax[tid + st] > samax[tid]) samax[tid] = samax[tid + st];
    }
    __syncthreads();
  }
  if (tid == 0) {
    atomicAdd(topkg, scnt[0]);
    amaxws[r] = 0xFFFFFFFFu - (u32)(samax[0] & 0xFFFFFFFFu);
  }
  for (int i = tid; i < 4096; i += 1024) { u32 h = hist[i]; if (h) atomicAdd(&ghist[i], h); }
}

// ---------------- K3a: pick level-1 bucket for k-th largest -----------
__global__ __launch_bounds__(1024) void k_sel1(const u32* __restrict__ ghist,
                                               const u32* __restrict__ topkg,
                                               u32* __restrict__ selb1,
                                               u32* __restrict__ selr1) {
  __shared__ u32 s[1024]; __shared__ u32 cs[1024];
  const int tid = threadIdx.x;
  u32 h[4]; u32 c = 0;
  #pragma unroll
  for (int j = 0; j < 4; ++j) { h[j] = ghist[tid * 4 + j]; c += h[j]; }
  cs[tid] = c; s[tid] = c;
  __syncthreads();
  for (int off = 1; off < 1024; off <<= 1) {
    u32 v = (tid + off < 1024) ? s[tid + off] : 0u;
    __syncthreads();
    s[tid] += v;
    __syncthreads();
  }
  const int topk = (int)(*topkg);
  float fr = (1.0f / 99999.0f) * (float)(25599744 - topk);  // B*(C-1)=25599744
  int k = (int)ceilf(fr); if (k < 1) k = 1;
  const u32 incl = s[tid], excl = incl - cs[tid];
  if ((int)excl < k && (int)incl >= k) {
    u32 cum = excl;
    for (int j = 3; j >= 0; --j) {
      cum += h[j];
      if ((int)cum >= k) { *selb1 = (u32)(tid * 4 + j); *selr1 = (u32)(k - (int)(cum - h[j])); break; }
    }
  }
}

// ---------------- K3b: collect keys in the selected bucket ------------
__global__ __launch_bounds__(1024) void k_collect(const float* __restrict__ cosb,
                                                  const int* __restrict__ lab,
                                                  const float* __restrict__ tgtws,
                                                  const u32* __restrict__ selb1,
                                                  u32* __restrict__ gcnt,
                                                  u32* __restrict__ buf) {
  const int tid = threadIdx.x, r = blockIdx.x;
  const u32 b1 = *selb1;
  const float tg = tgtws[r];
  const int lb = lab[r];
  const float* row = cosb + (size_t)r * NC;
  for (int i = tid; i < NC4; i += 1024) {
    float4 v4 = *(const float4*)(row + i * 4);
    float vv[4] = { v4.x, v4.y, v4.z, v4.w };
    #pragma unroll
    for (int j = 0; j < 4; ++j) {
      const int c = i * 4 + j;
      const float tmp = (c == lb) ? (tg - 2.0f) : vv[j];
      if (!(tmp > tg)) {
        u32 key = ordkey(tmp);
        if ((key >> 20) == b1) {
          u32 p = atomicAdd(gcnt, 1u);
          if (p < CAP) buf[p] = key;
        }
      }
    }
  }
}

// ---------------- K3c: exact neg_th from collected keys ---------------
__global__ __launch_bounds__(1024) void k_sel2(const u32* __restrict__ buf,
                                               const u32* __restrict__ gcnt,
                                               const u32* __restrict__ selb1,
                                               const u32* __restrict__ selr1,
                                               float* __restrict__ negth) {
  __shared__ u32 hist[4096];
  __shared__ u32 s[1024]; __shared__ u32 cs[1024];
  __shared__ u32 sb2, sr2;
  const int tid = threadIdx.x;
  const int n = (int)min(*gcnt, (u32)CAP);
  const u32 r1 = *selr1; const u32 b1 = *selb1;
  for (int i = tid; i < 4096; i += 1024) hist[i] = 0;
  __syncthreads();
  for (int i = tid; i < n; i += 1024) atomicAdd(&hist[(buf[i] >> 8) & 4095], 1u);
  __syncthreads();
  u32 h[4]; u32 c = 0;
  #pragma unroll
  for (int j = 0; j < 4; ++j) { h[j] = hist[tid * 4 + j]; c += h[j]; }
  cs[tid] = c; s[tid] = c;
  __syncthreads();
  for (int off = 1; off < 1024; off <<= 1) {
    u32 v = (tid + off < 1024) ? s[tid + off] : 0u;
    __syncthreads();
    s[tid] += v;
    __syncthreads();
  }
  const u32 incl = s[tid], excl = incl - cs[tid];
  if (excl < r1 && incl >= r1) {
    u32 cum = excl;
    for (int j = 3; j >= 0; --j) {
      cum += h[j];
      if (cum >= r1) { sb2 = (u32)(tid * 4 + j); sr2 = r1 - (cum - h[j]); break; }
    }
  }
  __syncthreads();
  const u32 b2 = sb2, r2 = sr2;
  for (int i = tid; i < 256; i += 1024) hist[i] = 0;
  __syncthreads();
  for (int i = tid; i < n; i += 1024) {
    u32 key = buf[i];
    if (((key >> 8) & 4095) == b2) atomicAdd(&hist[key & 255], 1u);
  }
  __syncthreads();
  if (tid == 0) {
    u32 cum = 0, b3 = 0;
    for (int j = 255; j >= 0; --j) { cum += hist[j]; if (cum >= r2) { b3 = (u32)j; break; } }
    u32 key = (b1 << 20) | (b2 << 8) | b3;
    u32 u = (key & 0x80000000u) ? (key & 0x7FFFFFFFu) : ~key;
    *negth = __uint_as_float(u);
  }
}

// ---------------- K4: per-row cnt/sumsq (cond) + sum(exp(64*cos)) -----
__global__ __launch_bounds__(1024) void k_stats(const float* __restrict__ cosb,
                                                const int* __restrict__ lab,
                                                const float* __restrict__ tgtws,
                                                const float* __restrict__ negth,
                                                u32* __restrict__ cntws,
                                                float* __restrict__ ssqws,
                                                float* __restrict__ sexpws) {
  __shared__ u32 sc[1024]; __shared__ float ss[1024]; __shared__ float se[1024];
  const int tid = threadIdx.x, r = blockIdx.x;
  const float tg = tgtws[r];
  const float th = *negth;
  const int lb = lab[r];
  const float* row = cosb + (size_t)r * NC;
  u32 cnt = 0; float ssq = 0.f, sexp = 0.f;
  for (int i = tid; i < NC4; i += 1024) {
    float4 v4 = *(const float4*)(row + i * 4);
    float vv[4] = { v4.x, v4.y, v4.z, v4.w };
    #pragma unroll
    for (int j = 0; j < 4; ++j) {
      const int c = i * 4 + j;
      const float v = vv[j];
      const float tmp = (c == lb) ? (tg - 2.0f) : v;
      const bool cond = (tmp <= tg) && (tmp > th);
      const float t2 = tmp * tmp;
      if (cond && (t2 > 0.0f)) { cnt++; ssq += t2; }
      sexp += expf(64.0f * v);
    }
  }
  sc[tid] = cnt; ss[tid] = ssq; se[tid] = sexp;
  __syncthreads();
  for (int st = 512; st > 0; st >>= 1) {
    if (tid < st) { sc[tid] += sc[tid + st]; ss[tid] += ss[tid + st]; se[tid] += se[tid + st]; }
    __syncthreads();
  }
  if (tid == 0) { cntws[r] = sc[0]; ssqws[r] = ss[0]; sexpws[r] = se[0]; }
}

// ---------------- K5: finalize loss & acc ------------------------------
__global__ void k_final(const int* __restrict__ lab, const float* __restrict__ tgtws,
                        const u32* __restrict__ cntws, const float* __restrict__ ssqws,
                        const float* __restrict__ sexpws, const u32* __restrict__ amaxws,
                        float* __restrict__ out) {
  __shared__ float sl[256]; __shared__ float sa[256];
  const int t = threadIdx.x;
  const float tg = tgtws[t];
  const float times = fmaxf((float)cntws[t], 1.0f);
  const float nm = ssqws[t] / times;
  const float tgm = (tg - 0.4f) - (1.0f + tg) * nm;
  const float logit = 64.0f * tgm;
  const float sexp = sexpws[t] - expf(64.0f * tg) + expf(logit);
  sl[t] = logf(sexp) - logit;
  sa[t] = (amaxws[t] == (u32)lab[t]) ? 1.0f : 0.0f;
  __syncthreads();
  for (int st = 128; st > 0; st >>= 1) {
    if (t < st) { sl[t] += sl[t + st]; sa[t] += sa[t + st]; }
    __syncthreads();
  }
  if (t == 0) { out[0] = sl[0] / 256.0f; out[1] = sa[0] / 256.0f; }
}

extern "C" void kernel_launch(void* const* d_in, const int* in_sizes, int n_in,
                              void* d_out, int out_size, void* d_ws, size_t ws_size,
                              hipStream_t stream) {
  const float* emb = (const float*)d_in[0];
  const int* lab = (const int*)d_in[1];
  const float* kern = (const float*)d_in[2];
  float* out = (float*)d_out;
  char* ws = (char*)d_ws;

  u16* embn = (u16*)(ws + OFF_EMBN);
  float* colss = (float*)(ws + OFF_COLSS);
  float* cosb = (float*)(ws + OFF_COS);
  float* tgtws = (float*)(ws + OFF_TGT);
  u32* cntws = (u32*)(ws + OFF_CNT);
  float* ssqws = (float*)(ws + OFF_SSQ);
  float* sexpws = (float*)(ws + OFF_SEXP);
  u32* amaxws = (u32*)(ws + OFF_AMAX);
  u32* scal = (u32*)(ws + OFF_SCAL);   // [0]=topk [1]=gcnt [2]=b1 [3]=r1 [4]=negth
  u32* ghist = (u32*)(ws + OFF_HIST);
  u32* buf = (u32*)(ws + OFF_BUF);

  hipMemsetAsync(ws + OFF_SCAL, 0, 256 + 16384, stream);  // scalars + ghist

  k_prep<<<NB, 128, 0, stream>>>(emb, embn);
  k_colss<<<(NC + 63) / 64, 256, 0, stream>>>(kern, colss);
  k_gemm<<<(NC + 127) / 128, 512, 0, stream>>>(kern, embn, colss, cosb);
  k_scan1<<<NB, 1024, 0, stream>>>(cosb, lab, tgtws, amaxws, &scal[0], ghist);
  k_sel1<<<1, 1024, 0, stream>>>(ghist, &scal[0], &scal[2], &scal[3]);
  k_collect<<<NB, 1024, 0, stream>>>(cosb, lab, tgtws, &scal[2], &scal[1], buf);
  k_sel2<<<1, 1024, 0, stream>>>(buf, &scal[1], &scal[2], &scal[3], (float*)&scal[4]);
  k_stats<<<NB, 1024, 0, stream>>>(cosb, lab, tgtws, (const float*)&scal[4], cntws, ssqws, sexpws);
  k_final<<<1, NB, 0, stream>>>(lab, tgtws, cntws, ssqws, sexpws, amaxws, out);
}